// Round 15
// baseline (146.342 us; speedup 1.0000x reference)
//
#include <hip/hip_runtime.h>
#include <hip/hip_bf16.h>

// Sizes: S=128, B=64, N=64, K=16, P=48, M=32
// Outputs: A [S,B,64,64] (C=4096), Bo [S,B,64,32] (C=2048), Cc [S,B,48,64] (C=3072)
#define SB 8192   // S*B

typedef float f4 __attribute__((ext_vector_type(4)));  // clang-native vec4

__device__ __forceinline__ float ftanh(float x) {
    // tanh(x) = 1 - 2/(exp(2x)+1)
    return fmaf(-2.f, __builtin_amdgcn_rcpf(1.f + __expf(2.f * x)), 1.f);
}

// ---------------------------------------------------------------------------
// Kernel 1: xg[row][g] = dot(x[row], W_ih[g]) + b_ih[g] + b_hh[g].
// Natural layout (no gate interleave) — the wave-wide scan reads row-contig.
// ---------------------------------------------------------------------------
__global__ __launch_bounds__(256) void xgate_kernel(
    const float* __restrict__ x,    // [8192][64]
    const float* __restrict__ Wih,  // [64][64]
    const float* __restrict__ bih,
    const float* __restrict__ bhh,
    float* __restrict__ xg)         // [8192][64]
{
    __shared__ float xs[4][64];
    const int tid = threadIdx.x;
    const int rl  = tid >> 6;
    const int g   = tid & 63;           // gate row: g = q*16 + t
    const size_t rowBase = (size_t)blockIdx.x * 4;

    xs[rl][g] = x[rowBase * 64 + tid];
    __syncthreads();

    const float* xr = xs[rl];
    float acc = bih[g] + bhh[g];
#pragma unroll
    for (int n = 0; n < 64; n += 4) {
        f4 wv = *reinterpret_cast<const f4*>(&Wih[g * 64 + n]);
        acc = fmaf(xr[n + 0], wv.x, acc);
        acc = fmaf(xr[n + 1], wv.y, acc);
        acc = fmaf(xr[n + 2], wv.z, acc);
        acc = fmaf(xr[n + 3], wv.w, acc);
    }
    xg[(rowBase + rl) * 64 + g] = acc;
}

// ---------------------------------------------------------------------------
// Kernel 2 (NEW): wave-wide LSTM scan. 64 blocks x 64 threads; block = batch.
// Lane g = q*16+t owns ONE gate row: 16-FMA chain + one exp/rcp per step.
// h broadcast: __shfl(h, k, 64) (lane k holds h[k]). i,f,g,o gathered with
// 4 shfls; all lanes compute c,h redundantly; q==0 lanes store w.
// Gate order (PyTorch): rows 0-15 i, 16-31 f, 32-47 g(tanh), 48-63 o.
// ---------------------------------------------------------------------------
__global__ __launch_bounds__(64) void lstm_scan_wave_kernel(
    const float* __restrict__ xg,   // [S*B][64]
    const float* __restrict__ Whh,  // [64][16]
    float* __restrict__ w)          // [S][B][16]
{
    const int b = blockIdx.x;       // batch
    const int g = threadIdx.x;      // gate row
    const int t = g & 15;
    const int q = g >> 4;

    float wrow[16];
#pragma unroll
    for (int k = 0; k < 16; ++k) wrow[k] = Whh[g * 16 + k];

    // branchless nonlinearity constants:
    // sigmoid: act = rcp(1+exp(-a));  tanh: act = 2*rcp(1+exp(-2a)) - 1
    const float sm = (q == 2) ? -2.f : -1.f;
    const float fa = (q == 2) ?  2.f :  1.f;
    const float fb = (q == 2) ? -1.f :  0.f;

    const float* xp = xg + b * 64 + g;       // stride 4096 floats per s
    float pf[4];
#pragma unroll
    for (int i = 0; i < 4; ++i) pf[i] = xp[(size_t)i * 4096];

    float h = 0.f, c = 0.f;
    for (int s = 0; s < 128; s += 4) {
#pragma unroll
        for (int u = 0; u < 4; ++u) {
            float a = pf[u];
            if (s + u + 4 < 128) pf[u] = xp[(size_t)(s + u + 4) * 4096];

            // a += sum_k Whh[g][k] * h[k]  (h[k] lives on lane k)
#pragma unroll
            for (int k = 0; k < 16; ++k)
                a = fmaf(__shfl(h, k, 64), wrow[k], a);

            float e   = __expf(a * sm);
            float act = fmaf(fa, __builtin_amdgcn_rcpf(1.f + e), fb);

            float i_ = __shfl(act, t,      64);
            float f_ = __shfl(act, t + 16, 64);
            float g_ = __shfl(act, t + 32, 64);
            float o_ = __shfl(act, t + 48, 64);

            c = fmaf(f_, c, i_ * g_);
            h = o_ * ftanh(c);

            if (q == 0)
                w[((size_t)(s + u) * 64 + b) * 16 + t] = h;
        }
    }
}

// ---------------------------------------------------------------------------
// Kernel 3 (R6-exact): out[row][i] = sum_k w[row][k]*M[k][i].
// 2304 blocks = 9/CU; wave-uniform w -> scalar s_load; m[16] in registers;
// plain coalesced f4 stores. No LDS, no barriers.
// ---------------------------------------------------------------------------
__global__ __launch_bounds__(256) void wsum_all_kernel(
    const float* __restrict__ w,   // [8192][16]
    const float* __restrict__ As, const float* __restrict__ Bs,
    const float* __restrict__ Cs,
    float* __restrict__ outA, float* __restrict__ outB, float* __restrict__ outC)
{
    const int tid = threadIdx.x;
    const int bid = blockIdx.x;

    const float* M; float* o; int C, local, colTiles;
    if (bid < 1024)      { M = As; o = outA; C = 4096; local = bid;        colTiles = 4; }
    else if (bid < 1536) { M = Bs; o = outB; C = 2048; local = bid - 1024; colTiles = 2; }
    else                 { M = Cs; o = outC; C = 3072; local = bid - 1536; colTiles = 3; }

    const int colTile  = local % colTiles;
    const int rowStart = (local / colTiles) * 32;
    const int i4 = colTile * 1024 + tid * 4;

    f4 m[16];
#pragma unroll
    for (int k = 0; k < 16; ++k)
        m[k] = *reinterpret_cast<const f4*>(&M[(size_t)k * C + i4]);

    const float* wp = w + (size_t)rowStart * 16;   // wave-uniform
    float* op = o + (size_t)rowStart * C + i4;

#pragma unroll 2
    for (int r = 0; r < 32; ++r) {
        f4 acc = (f4)0.f;
#pragma unroll
        for (int k = 0; k < 16; ++k)
            acc += wp[r * 16 + k] * m[k];          // uniform -> s_load
        *reinterpret_cast<f4*>(op) = acc;
        op += C;
    }
}

// ---------------------------------------------------------------------------
extern "C" void kernel_launch(void* const* d_in, const int* in_sizes, int n_in,
                              void* d_out, int out_size, void* d_ws, size_t ws_size,
                              hipStream_t stream) {
    const float* state = (const float*)d_in[0];
    const float* W_ih  = (const float*)d_in[1];
    const float* W_hh  = (const float*)d_in[2];
    const float* b_ih  = (const float*)d_in[3];
    const float* b_hh  = (const float*)d_in[4];
    const float* As    = (const float*)d_in[5];
    const float* Bs    = (const float*)d_in[6];
    const float* Cs    = (const float*)d_in[7];
    float* out = (float*)d_out;

    float* xg = (float*)d_ws;            // 8192*64 floats
    float* w  = xg + (size_t)SB * 64;    // 8192*16 floats

    xgate_kernel<<<SB / 4, 256, 0, stream>>>(state, W_ih, b_ih, b_hh, xg);
    lstm_scan_wave_kernel<<<64, 64, 0, stream>>>(xg, W_hh, w);

    float* outA = out;
    float* outB = out + (size_t)SB * 4096;
    float* outC = out + (size_t)SB * 4096 + (size_t)SB * 2048;

    wsum_all_kernel<<<2304, 256, 0, stream>>>(w, As, Bs, Cs, outA, outB, outC);
}

// Round 16
// 118.299 us; speedup vs baseline: 1.2371x; 1.2371x over previous
//
#include <hip/hip_runtime.h>
#include <hip/hip_bf16.h>

// Sizes: S=128, B=64, N=64, K=16, P=48, M=32
// Outputs: A [S,B,64,64] (C=4096), Bo [S,B,64,32] (C=2048), Cc [S,B,48,64] (C=3072)
#define SB 8192    // S*B
#define NCONS 480  // consumer blocks in fused kernel
#define NFLAGS 8   // one flag per 16 scan steps

typedef float f4 __attribute__((ext_vector_type(4)));  // clang-native vec4

__device__ __forceinline__ float fsig(float x) {
    return __builtin_amdgcn_rcpf(1.f + __expf(-x));
}
__device__ __forceinline__ float ftanh(float x) {
    return fmaf(-2.f, __builtin_amdgcn_rcpf(1.f + __expf(2.f * x)), 1.f);
}

// ---------------------------------------------------------------------------
// Kernel 1: gate-interleaved input projection + zero the 8 chunk flags.
// ---------------------------------------------------------------------------
__global__ __launch_bounds__(256) void xgate_kernel(
    const float* __restrict__ x,    // [8192][64]
    const float* __restrict__ Wih,  // [64][64]
    const float* __restrict__ bih,
    const float* __restrict__ bhh,
    float* __restrict__ xg,         // [8192][16][4] gate-interleaved
    unsigned int* __restrict__ flags)
{
    __shared__ float xs[4][64];
    const int tid = threadIdx.x;
    if (blockIdx.x == 0 && tid < NFLAGS) flags[tid] = 0u;

    const int rl  = tid >> 6;
    const int g   = tid & 63;           // weight row: g = q*16 + t
    const size_t rowBase = (size_t)blockIdx.x * 4;

    xs[rl][g] = x[rowBase * 64 + tid];
    __syncthreads();

    const float* xr = xs[rl];
    float acc = bih[g] + bhh[g];
#pragma unroll
    for (int n = 0; n < 64; n += 4) {
        f4 wv = *reinterpret_cast<const f4*>(&Wih[g * 64 + n]);
        acc = fmaf(xr[n + 0], wv.x, acc);
        acc = fmaf(xr[n + 1], wv.y, acc);
        acc = fmaf(xr[n + 2], wv.z, acc);
        acc = fmaf(xr[n + 3], wv.w, acc);
    }
    xg[(rowBase + rl) * 64 + (g & 15) * 4 + (g >> 4)] = acc;
}

// ---------------------------------------------------------------------------
// Kernel 2 (fused): blocks 0-15 = scan producers at s_setprio(2) (win issue
// arbitration vs streaming consumers on the same CU -> no latency stretch);
// blocks 16-495 = wsum consumers gated per 16-step chunk by relaxed sleep-poll
// + one agent ACQUIRE. Deadlock-free: producers dispatch first, never wait.
// ---------------------------------------------------------------------------
__global__ __launch_bounds__(256, 2) void fused_kernel(
    const float* __restrict__ xg,   // [S][B][16][4]
    const float* __restrict__ Whh,  // [64][16]
    float* __restrict__ w,          // [S][B][16]
    unsigned int* __restrict__ flags,
    const float* __restrict__ As, const float* __restrict__ Bs,
    const float* __restrict__ Cs,
    float* __restrict__ outA, float* __restrict__ outB, float* __restrict__ outC)
{
    __shared__ f4 ws[128];                  // consumer w-tile stage (32 rows)
    __shared__ alignas(16) float hs[64];    // scan h broadcast
    const int tid = threadIdx.x;
    const int bid = blockIdx.x;

    if (bid < 16) {
        // ---------------- producer: LSTM scan (wave 0 only) ----------------
        if (tid >= 64) return;
        __builtin_amdgcn_s_setprio(2);      // protect the latency chain
        const int t  = tid & 15;
        const int b4 = tid >> 4;
        const int b  = bid * 4 + b4;

        float wi[16], wf[16], wg[16], wo[16];
#pragma unroll
        for (int k = 0; k < 16; ++k) {
            wi[k] = Whh[(0 * 16 + t) * 16 + k];
            wf[k] = Whh[(1 * 16 + t) * 16 + k];
            wg[k] = Whh[(2 * 16 + t) * 16 + k];
            wo[k] = Whh[(3 * 16 + t) * 16 + k];
        }

        const f4* xp = reinterpret_cast<const f4*>(xg) + b * 16 + t;
        f4 xv = xp[0];
        float h = 0.f, c = 0.f;
        for (int s = 0; s < 128; ++s) {
            f4 nx = (s < 127) ? xp[(size_t)(s + 1) * 1024] : (f4)0.f;

            hs[tid] = h;                    // wave-local LDS round-trip
            asm volatile("s_waitcnt lgkmcnt(0)" ::: "memory");
            union { f4 v[4]; float f[16]; } hh;
            hh.v[0] = *reinterpret_cast<const f4*>(&hs[b4 * 16 + 0]);
            hh.v[1] = *reinterpret_cast<const f4*>(&hs[b4 * 16 + 4]);
            hh.v[2] = *reinterpret_cast<const f4*>(&hs[b4 * 16 + 8]);
            hh.v[3] = *reinterpret_cast<const f4*>(&hs[b4 * 16 + 12]);

            float ai = xv.x, af = xv.y, ag = xv.z, ao = xv.w;
#pragma unroll
            for (int k = 0; k < 16; ++k) {
                float hk = hh.f[k];
                ai = fmaf(hk, wi[k], ai);
                af = fmaf(hk, wf[k], af);
                ag = fmaf(hk, wg[k], ag);
                ao = fmaf(hk, wo[k], ao);
            }
            float ig = fsig(ai), fg = fsig(af), og = fsig(ao);
            float gt = ftanh(ag);
            c = fg * c + ig * gt;
            h = og * ftanh(c);
            w[((size_t)s * 64 + b) * 16 + t] = h;
            xv = nx;

            if ((s & 15) == 15 && tid == 0)
                __hip_atomic_fetch_add(&flags[s >> 4], 1u, __ATOMIC_RELEASE,
                                       __HIP_MEMORY_SCOPE_AGENT);
        }
        return;
    }

    // ---------------- consumers: weighted-sum tiles in s-order --------------
    // tile T in [0,2304): s = T/18; r = T%18 -> ct = r>>1 (0-8), bhalf = r&1.
    const int j = bid - 16;
    int have = -1;
    for (int T = j; T < 2304; T += NCONS) {
        const int s    = T / 18;
        const int r    = T % 18;
        const int need = s >> 4;            // 16-step chunk

        const int ct = r >> 1;
        const int rowStart = s * 64 + (r & 1) * 32;

        const float* M; float* o; int C, cto;
        if (ct < 4)      { M = As; o = outA; C = 4096; cto = ct; }
        else if (ct < 6) { M = Bs; o = outB; C = 2048; cto = ct - 4; }
        else             { M = Cs; o = outC; C = 3072; cto = ct - 6; }
        const int i4 = cto * 1024 + tid * 4;

        // matrix slice into registers BEFORE the wait (hide under polling)
        f4 m[16];
#pragma unroll
        for (int q = 0; q < 16; ++q)
            m[q] = *reinterpret_cast<const f4*>(&M[(size_t)q * C + i4]);

        if (need != have) {
            if (tid == 0) {
                while (__hip_atomic_load(&flags[need], __ATOMIC_RELAXED,
                                         __HIP_MEMORY_SCOPE_AGENT) < 16u)
                    __builtin_amdgcn_s_sleep(64);   // ~1.7 us between polls
                (void)__hip_atomic_load(&flags[need], __ATOMIC_ACQUIRE,
                                        __HIP_MEMORY_SCOPE_AGENT);
            }
            __syncthreads();                        // all threads see fresh w
            have = need;
        }

        // stage 32 rows of w (512 floats = 128 f4) via VECTOR loads
        if (tid < 128)
            ws[tid] = reinterpret_cast<const f4*>(w)[rowStart * 4 + tid];
        __syncthreads();                            // ws ready

        float* op = o + (size_t)rowStart * C + i4;
#pragma unroll 2
        for (int r2 = 0; r2 < 32; ++r2) {
            f4 w0 = ws[r2 * 4 + 0];                 // ds_read_b128 broadcast
            f4 w1 = ws[r2 * 4 + 1];
            f4 w2 = ws[r2 * 4 + 2];
            f4 w3 = ws[r2 * 4 + 3];
            f4 acc = (f4)0.f;
#pragma unroll
            for (int q = 0; q < 4; ++q) acc += w0[q] * m[q + 0];
#pragma unroll
            for (int q = 0; q < 4; ++q) acc += w1[q] * m[q + 4];
#pragma unroll
            for (int q = 0; q < 4; ++q) acc += w2[q] * m[q + 8];
#pragma unroll
            for (int q = 0; q < 4; ++q) acc += w3[q] * m[q + 12];
            *reinterpret_cast<f4*>(op) = acc;
            op += C;
        }
        __syncthreads();                            // protect ws before restage
    }
}

// ---------------------------------------------------------------------------
extern "C" void kernel_launch(void* const* d_in, const int* in_sizes, int n_in,
                              void* d_out, int out_size, void* d_ws, size_t ws_size,
                              hipStream_t stream) {
    const float* state = (const float*)d_in[0];
    const float* W_ih  = (const float*)d_in[1];
    const float* W_hh  = (const float*)d_in[2];
    const float* b_ih  = (const float*)d_in[3];
    const float* b_hh  = (const float*)d_in[4];
    const float* As    = (const float*)d_in[5];
    const float* Bs    = (const float*)d_in[6];
    const float* Cs    = (const float*)d_in[7];
    float* out = (float*)d_out;

    float* xg = (float*)d_ws;                     // 8192*64 floats
    float* w  = xg + (size_t)SB * 64;             // 8192*16 floats
    unsigned int* flags = (unsigned int*)(w + (size_t)SB * 16);   // 8 flags

    float* outA = out;
    float* outB = out + (size_t)SB * 4096;
    float* outC = out + (size_t)SB * 4096 + (size_t)SB * 2048;

    xgate_kernel<<<SB / 4, 256, 0, stream>>>(state, W_ih, b_ih, b_hh, xg, flags);
    fused_kernel<<<16 + NCONS, 256, 0, stream>>>(xg, W_hh, w, flags,
                                                 As, Bs, Cs, outA, outB, outC);
}

// Round 19
// 105.233 us; speedup vs baseline: 1.3906x; 1.1242x over previous
//
#include <hip/hip_runtime.h>
#include <hip/hip_bf16.h>

// Sizes: S=128, B=64, N=64, K=16, P=48, M=32
// Outputs: A [S,B,64,64] (C=4096), Bo [S,B,64,32] (C=2048), Cc [S,B,48,64] (C=3072)
#define SB 8192   // S*B

typedef float f4 __attribute__((ext_vector_type(4)));  // clang-native vec4

__device__ __forceinline__ float fsig(float x) {
    return __builtin_amdgcn_rcpf(1.f + __expf(-x));
}
__device__ __forceinline__ float ftanh(float x) {
    // tanh(x) = 1 - 2/(exp(2x)+1); correct limits at +-inf via rcp(inf)=0
    return fmaf(-2.f, __builtin_amdgcn_rcpf(1.f + __expf(2.f * x)), 1.f);
}

// ---------------------------------------------------------------------------
// Kernel 1 (R6-exact): xg[row][t*4+q] = dot(x[row], W_ih[q*16+t]) + b.
// Gate-interleaved so the scan loads one float4 per (step, batch, unit).
// ---------------------------------------------------------------------------
__global__ __launch_bounds__(256) void xgate_kernel(
    const float* __restrict__ x,    // [8192][64]
    const float* __restrict__ Wih,  // [64][64]
    const float* __restrict__ bih,
    const float* __restrict__ bhh,
    float* __restrict__ xg)         // [8192][16][4] gate-interleaved
{
    __shared__ float xs[4][64];
    const int tid = threadIdx.x;
    const int rl  = tid >> 6;
    const int g   = tid & 63;           // weight row: g = q*16 + t
    const size_t rowBase = (size_t)blockIdx.x * 4;

    xs[rl][g] = x[rowBase * 64 + tid];
    __syncthreads();

    const float* xr = xs[rl];
    float acc = bih[g] + bhh[g];
#pragma unroll
    for (int n = 0; n < 64; n += 4) {
        f4 wv = *reinterpret_cast<const f4*>(&Wih[g * 64 + n]);
        acc = fmaf(xr[n + 0], wv.x, acc);
        acc = fmaf(xr[n + 1], wv.y, acc);
        acc = fmaf(xr[n + 2], wv.z, acc);
        acc = fmaf(xr[n + 3], wv.w, acc);
    }
    xg[(rowBase + rl) * 64 + (g & 15) * 4 + (g >> 4)] = acc;
}

// ---------------------------------------------------------------------------
// Kernel 2: LSTM scan, 16 blocks x 1 wave (64 thr). Thread owns (b, t).
// KEY CHANGE vs R6: NO __syncthreads / NO s_waitcnt asm in the step loop.
// Single wave => same-wave DS FIFO makes the h write->read exchange correct
// with only a compiler fence; no vmcnt(0) ever drains the w-stores or the
// 4-deep xg prefetch on the serial chain.
// ---------------------------------------------------------------------------
__global__ __launch_bounds__(64) void lstm_scan_kernel(
    const float* __restrict__ xg,   // [S][B][16][4]
    const float* __restrict__ Whh,  // [64][16]
    float* __restrict__ w)          // [S][B][16]
{
    __shared__ alignas(16) float hs[64];
    const int tid = threadIdx.x;
    const int t  = tid & 15;        // hidden unit
    const int b4 = tid >> 4;        // local batch (0..3)
    const int b  = blockIdx.x * 4 + b4;

    float wi[16], wf[16], wg[16], wo[16];
#pragma unroll
    for (int k = 0; k < 16; ++k) {
        wi[k] = Whh[(0 * 16 + t) * 16 + k];
        wf[k] = Whh[(1 * 16 + t) * 16 + k];
        wg[k] = Whh[(2 * 16 + t) * 16 + k];
        wo[k] = Whh[(3 * 16 + t) * 16 + k];
    }

    // f4 view: element (s,b,t) at f4-index (s*64+b)*16 + t; s-stride = 1024
    const f4* xp = reinterpret_cast<const f4*>(xg) + b * 16 + t;

    // 4-deep register prefetch (statically indexed via unroll)
    f4 pf[4];
#pragma unroll
    for (int i = 0; i < 4; ++i) pf[i] = xp[(size_t)i * 1024];

    float h = 0.f, c = 0.f;
    for (int s = 0; s < 128; s += 4) {
#pragma unroll
        for (int u = 0; u < 4; ++u) {
            f4 xv = pf[u];
            const int nidx = (s + u + 4 < 128) ? (s + u + 4) : 127;
            pf[u] = xp[(size_t)nidx * 1024];     // refill 4 ahead (discardable tail)

            // publish h[b][t]; same-wave DS FIFO => reads below see it.
            hs[tid] = h;
            asm volatile("" ::: "memory");       // compiler fence only (no waitcnt)
            union { f4 v[4]; float f[16]; } hh;
            hh.v[0] = *reinterpret_cast<const f4*>(&hs[b4 * 16 + 0]);
            hh.v[1] = *reinterpret_cast<const f4*>(&hs[b4 * 16 + 4]);
            hh.v[2] = *reinterpret_cast<const f4*>(&hs[b4 * 16 + 8]);
            hh.v[3] = *reinterpret_cast<const f4*>(&hs[b4 * 16 + 12]);

            float ai = xv.x, af = xv.y, ag = xv.z, ao = xv.w;
#pragma unroll
            for (int k = 0; k < 16; ++k) {
                float hk = hh.f[k];
                ai = fmaf(hk, wi[k], ai);
                af = fmaf(hk, wf[k], af);
                ag = fmaf(hk, wg[k], ag);
                ao = fmaf(hk, wo[k], ao);
            }
            float ig = fsig(ai), fg = fsig(af), og = fsig(ao);
            float gt = ftanh(ag);
            c = fg * c + ig * gt;
            h = og * ftanh(c);
            w[((size_t)(s + u) * 64 + b) * 16 + t] = h;   // fire-and-forget
        }
    }
}

// ---------------------------------------------------------------------------
// Kernel 3 (R6-exact): out[row][i] = sum_k w[row][k]*M[k][i].
// 2304 blocks = 9/CU; wave-uniform w -> scalar s_load; m[16] in registers;
// plain coalesced f4 stores. No LDS, no barriers.
// ---------------------------------------------------------------------------
__global__ __launch_bounds__(256) void wsum_all_kernel(
    const float* __restrict__ w,   // [8192][16]
    const float* __restrict__ As, const float* __restrict__ Bs,
    const float* __restrict__ Cs,
    float* __restrict__ outA, float* __restrict__ outB, float* __restrict__ outC)
{
    const int tid = threadIdx.x;
    const int bid = blockIdx.x;

    const float* M; float* o; int C, local, colTiles;
    if (bid < 1024)      { M = As; o = outA; C = 4096; local = bid;        colTiles = 4; }
    else if (bid < 1536) { M = Bs; o = outB; C = 2048; local = bid - 1024; colTiles = 2; }
    else                 { M = Cs; o = outC; C = 3072; local = bid - 1536; colTiles = 3; }

    const int colTile  = local % colTiles;
    const int rowStart = (local / colTiles) * 32;
    const int i4 = colTile * 1024 + tid * 4;

    f4 m[16];
#pragma unroll
    for (int k = 0; k < 16; ++k)
        m[k] = *reinterpret_cast<const f4*>(&M[(size_t)k * C + i4]);

    const float* wp = w + (size_t)rowStart * 16;   // wave-uniform
    float* op = o + (size_t)rowStart * C + i4;

#pragma unroll 2
    for (int r = 0; r < 32; ++r) {
        f4 acc = (f4)0.f;
#pragma unroll
        for (int k = 0; k < 16; ++k)
            acc += wp[r * 16 + k] * m[k];          // uniform -> s_load
        *reinterpret_cast<f4*>(op) = acc;
        op += C;
    }
}

// ---------------------------------------------------------------------------
extern "C" void kernel_launch(void* const* d_in, const int* in_sizes, int n_in,
                              void* d_out, int out_size, void* d_ws, size_t ws_size,
                              hipStream_t stream) {
    const float* state = (const float*)d_in[0];
    const float* W_ih  = (const float*)d_in[1];
    const float* W_hh  = (const float*)d_in[2];
    const float* b_ih  = (const float*)d_in[3];
    const float* b_hh  = (const float*)d_in[4];
    const float* As    = (const float*)d_in[5];
    const float* Bs    = (const float*)d_in[6];
    const float* Cs    = (const float*)d_in[7];
    float* out = (float*)d_out;

    float* xg = (float*)d_ws;            // 8192*64 floats
    float* w  = xg + (size_t)SB * 64;    // 8192*16 floats

    xgate_kernel<<<SB / 4, 256, 0, stream>>>(state, W_ih, b_ih, b_hh, xg);
    lstm_scan_kernel<<<16, 64, 0, stream>>>(xg, W_hh, w);

    float* outA = out;
    float* outB = out + (size_t)SB * 4096;
    float* outC = out + (size_t)SB * 4096 + (size_t)SB * 2048;

    wsum_all_kernel<<<2304, 256, 0, stream>>>(w, As, Bs, Cs, outA, outB, outC);
}